// Round 2
// baseline (1703.520 us; speedup 1.0000x reference)
//
#include <hip/hip_runtime.h>
#include <hip/hip_bf16.h>
#include <cstdint>
#include <cstddef>
#include <type_traits>

#define TPB 256

typedef __attribute__((ext_vector_type(8))) short short8;
typedef __attribute__((ext_vector_type(4))) float floatx4;

__device__ __forceinline__ float bf2f(const __hip_bfloat16 x) { return __bfloat162float(x); }

__device__ __forceinline__ float ld_as_f(const float* p) { return *p; }
__device__ __forceinline__ float ld_as_f(const __hip_bfloat16* p) { return bf2f(*p); }

__device__ __forceinline__ void store_c(float* C, size_t off, float v) { C[off] = v; }
__device__ __forceinline__ void store_c(__hip_bfloat16* C, size_t off, float v) { C[off] = __float2bfloat16(v); }

union Bf8 { __hip_bfloat16 h[8]; uint4 u; };

// Load 8 contiguous elements starting at src (guaranteed in-bounds, element
// offset divisible by 4) and return them as 8 packed bf16.
__device__ __forceinline__ uint4 load8_bf16(const float* src) {
    const float4 a = *(const float4*)(src);
    const float4 b = *(const float4*)(src + 4);
    Bf8 t;
    t.h[0] = __float2bfloat16(a.x); t.h[1] = __float2bfloat16(a.y);
    t.h[2] = __float2bfloat16(a.z); t.h[3] = __float2bfloat16(a.w);
    t.h[4] = __float2bfloat16(b.x); t.h[5] = __float2bfloat16(b.y);
    t.h[6] = __float2bfloat16(b.z); t.h[7] = __float2bfloat16(b.w);
    return t.u;
}
__device__ __forceinline__ uint4 load8_bf16(const __hip_bfloat16* src) {
    // element offset divisible by 4 -> 8-byte aligned; use two uint2 loads
    uint4 r;
    const uint2 a = *(const uint2*)(src);
    const uint2 b = *(const uint2*)(src + 4);
    r.x = a.x; r.y = a.y; r.z = b.x; r.w = b.y;
    return r;
}

// C[M,N] = A[M,K] @ B[N,K]^T  (+ bias[n]) (+= existing C if ACC)
// A,B converted to bf16 during LDS staging; fp32 MFMA accumulate.
// Requires lda % 4 == 0 and ldb % 4 == 0. Edge-guarded in M, N, K.
template<typename TA, typename TB, typename OutT, bool ACC, bool BIAS>
__global__ __launch_bounds__(TPB)
void gemm_bt(const TA* __restrict__ A, int lda,
             const TB* __restrict__ Bm, int ldb,
             OutT* __restrict__ C, int ldc,
             const float* __restrict__ bias,
             int M, int N, int K)
{
    __shared__ __hip_bfloat16 As[128][40];   // +8 bf16 pad (row = 80 B, 16B-aligned)
    __shared__ __hip_bfloat16 Bs[128][40];

    const int tid  = threadIdx.x;
    const int lane = tid & 63;
    const int wave = tid >> 6;
    const int wm   = (wave & 1) * 64;
    const int wn   = (wave >> 1) * 64;
    const int l15  = lane & 15;
    const int quad = lane >> 4;
    const long tileM = (long)blockIdx.y * 128;
    const long tileN = (long)blockIdx.x * 128;

    floatx4 acc[4][4];
#pragma unroll
    for (int i = 0; i < 4; ++i)
#pragma unroll
        for (int j = 0; j < 4; ++j)
            acc[i][j] = (floatx4){0.f, 0.f, 0.f, 0.f};

    for (int k0 = 0; k0 < K; k0 += 32) {
#pragma unroll
        for (int p = 0; p < 2; ++p) {
            const int idx = (p * TPB + tid) * 8;   // 0..4088, step 8
            const int r = idx >> 5;                // row in tile 0..127
            const int c = idx & 31;                // k offset {0,8,16,24}
            {   // A tile
                const long gr = tileM + r;
                const int  gc = k0 + c;
                uint4 v;
                if (gr < M && gc + 8 <= K) {
                    v = load8_bf16(A + (size_t)gr * lda + gc);
                } else {
                    Bf8 t;
#pragma unroll
                    for (int e = 0; e < 8; ++e)
                        t.h[e] = (gr < M && (gc + e) < K)
                                   ? __float2bfloat16(ld_as_f(A + (size_t)gr * lda + gc + e))
                                   : __float2bfloat16(0.f);
                    v = t.u;
                }
                *(uint4*)(&As[r][c]) = v;
            }
            {   // B tile
                const long gr = tileN + r;
                const int  gc = k0 + c;
                uint4 v;
                if (gr < N && gc + 8 <= K) {
                    v = load8_bf16(Bm + (size_t)gr * ldb + gc);
                } else {
                    Bf8 t;
#pragma unroll
                    for (int e = 0; e < 8; ++e)
                        t.h[e] = (gr < N && (gc + e) < K)
                                   ? __float2bfloat16(ld_as_f(Bm + (size_t)gr * ldb + gc + e))
                                   : __float2bfloat16(0.f);
                    v = t.u;
                }
                *(uint4*)(&Bs[r][c]) = v;
            }
        }
        __syncthreads();

        short8 af[4], bfg[4];
#pragma unroll
        for (int i = 0; i < 4; ++i)
            af[i] = *(const short8*)(&As[wm + i * 16 + l15][quad * 8]);
#pragma unroll
        for (int j = 0; j < 4; ++j)
            bfg[j] = *(const short8*)(&Bs[wn + j * 16 + l15][quad * 8]);
#pragma unroll
        for (int i = 0; i < 4; ++i)
#pragma unroll
            for (int j = 0; j < 4; ++j)
                acc[i][j] = __builtin_amdgcn_mfma_f32_16x16x32_bf16(af[i], bfg[j], acc[i][j], 0, 0, 0);
        __syncthreads();
    }

#pragma unroll
    for (int i = 0; i < 4; ++i) {
#pragma unroll
        for (int j = 0; j < 4; ++j) {
            const long n = tileN + wn + j * 16 + l15;
            if (n >= N) continue;
            float bv = 0.f;
            if constexpr (BIAS) bv = bias[n];
#pragma unroll
            for (int r = 0; r < 4; ++r) {
                const long m = tileM + wm + i * 16 + quad * 4 + r;
                if (m >= M) continue;
                float v = acc[i][j][r] + bv;
                const size_t off = (size_t)m * ldc + n;
                if constexpr (ACC) v += ((const float*)C)[off];
                store_c(C, off, v);
            }
        }
    }
}

// Bahdanau attention, one batch row per block.
// scores[n] = sum_h tanh(Wh[b,h] + U[b,n,h] + bias[h]) * w[h]; softmax over n;
// dst[b*dst_ld + 0:D] = sum_n a[n] * feats[b,n,0:D]
__global__ __launch_bounds__(TPB)
void attn_kernel(const float* __restrict__ Wh,
                 const __hip_bfloat16* __restrict__ U,
                 const float* __restrict__ feats,
                 const float* __restrict__ bias,
                 const float* __restrict__ w,
                 __hip_bfloat16* __restrict__ dst,
                 int dst_ld, int N, int D)
{
    const int b = blockIdx.x;
    const int tid = threadIdx.x;
    const int lane = tid & 63;
    const int wave = tid >> 6;
    __shared__ float sc[64];

    const float* whb = Wh + (size_t)b * 512;
    for (int n = wave; n < N; n += 4) {
        const __hip_bfloat16* un = U + ((size_t)b * N + n) * 512;
        float s = 0.f;
        for (int h = lane; h < 512; h += 64)
            s += tanhf(whb[h] + bf2f(un[h]) + bias[h]) * w[h];
#pragma unroll
        for (int off = 32; off > 0; off >>= 1) s += __shfl_down(s, off);
        if (lane == 0) sc[n] = s;
    }
    __syncthreads();
    if (tid == 0) {
        float mx = -3.4e38f;
        for (int n = 0; n < N; ++n) mx = fmaxf(mx, sc[n]);
        float sum = 0.f;
        for (int n = 0; n < N; ++n) { float e = expf(sc[n] - mx); sc[n] = e; sum += e; }
        float inv = 1.f / sum;
        for (int n = 0; n < N; ++n) sc[n] *= inv;
    }
    __syncthreads();
    for (int d = tid; d < D; d += TPB) {
        float a = 0.f;
        for (int n = 0; n < N; ++n)
            a += sc[n] * feats[((size_t)b * N + n) * D + d];
        dst[(size_t)b * dst_ld + d] = __float2bfloat16(a);
    }
}

// fp32 src -> bf16 dst, 2D strided copy
__global__ __launch_bounds__(TPB)
void cvt_copy_2d(const float* __restrict__ src, int src_ld,
                 __hip_bfloat16* __restrict__ dst, int dst_ld,
                 int rows, int cols)
{
    const int idx = blockIdx.x * TPB + threadIdx.x;
    if (idx >= rows * cols) return;
    const int r = idx / cols, c = idx - r * cols;
    dst[(size_t)r * dst_ld + c] = __float2bfloat16(src[(size_t)r * src_ld + c]);
}

__device__ __forceinline__ float sigmoidf_(float x) { return 1.f / (1.f + expf(-x)); }

__global__ __launch_bounds__(TPB)
void lstm_kernel(const float* __restrict__ gates,
                 const float* __restrict__ b_ih,
                 const float* __restrict__ b_hh,
                 const float* __restrict__ c0,
                 float* __restrict__ out_h,
                 float* __restrict__ out_c,
                 __hip_bfloat16* __restrict__ h_ws)
{
    const int idx = blockIdx.x * TPB + threadIdx.x;   // B*H threads
    if (idx >= 1024 * 512) return;
    const int hh = idx & 511;
    const float* g = gates + (size_t)(idx >> 9) * 2048;
    const float gi = g[hh]        + b_ih[hh]        + b_hh[hh];
    const float gf = g[512 + hh]  + b_ih[512 + hh]  + b_hh[512 + hh];
    const float gg = g[1024 + hh] + b_ih[1024 + hh] + b_hh[1024 + hh];
    const float go = g[1536 + hh] + b_ih[1536 + hh] + b_hh[1536 + hh];
    const float c = sigmoidf_(gf) * c0[idx] + sigmoidf_(gi) * tanhf(gg);
    const float h = sigmoidf_(go) * tanhf(c);
    out_h[idx] = h;
    out_c[idx] = c;
    h_ws[idx]  = __float2bfloat16(h);
}

// in-place log-softmax over each row of [B, V] fp32
__global__ __launch_bounds__(TPB)
void logsoftmax_kernel(float* __restrict__ logits, int V)
{
    const int b = blockIdx.x;
    const int tid = threadIdx.x;
    float* row = logits + (size_t)b * V;
    __shared__ float red[TPB];

    float mx = -3.4e38f;
    for (int v = tid; v < V; v += TPB) mx = fmaxf(mx, row[v]);
    red[tid] = mx; __syncthreads();
    for (int s = TPB / 2; s > 0; s >>= 1) {
        if (tid < s) red[tid] = fmaxf(red[tid], red[tid + s]);
        __syncthreads();
    }
    mx = red[0]; __syncthreads();

    float sum = 0.f;
    for (int v = tid; v < V; v += TPB) sum += expf(row[v] - mx);
    red[tid] = sum; __syncthreads();
    for (int s = TPB / 2; s > 0; s >>= 1) {
        if (tid < s) red[tid] += red[tid + s];
        __syncthreads();
    }
    const float lse = mx + logf(red[0]);

    for (int v = tid; v < V; v += TPB)
        row[v] = row[v] - lse;
}

extern "C" void kernel_launch(void* const* d_in, const int* in_sizes, int n_in,
                              void* d_out, int out_size, void* d_ws, size_t ws_size,
                              hipStream_t stream)
{
    (void)in_sizes; (void)n_in; (void)out_size; (void)ws_size;
    const int B = 1024, H = 512, S = 300, E = 512, V = 50257;
    const int NO = 36, NA = 26, NV = 26, NOS = 20;

    typedef const float* cf;
    cf objects   = (cf)d_in[0];
    cf action    = (cf)d_in[1];
    cf video     = (cf)d_in[2];
    cf obj_sem   = (cf)d_in[3];
    cf act_sem   = (cf)d_in[4];
    cf vid_sem   = (cf)d_in[5];
    cf embed     = (cf)d_in[6];
    cf h0        = (cf)d_in[7];
    cf c0        = (cf)d_in[8];
    cf W_w       = (cf)d_in[9];
    cf Uo_w      = (cf)d_in[10];
    cf bo        = (cf)d_in[11];
    cf wo_w      = (cf)d_in[12];
    cf Uos_w     = (cf)d_in[13];
    cf bos       = (cf)d_in[14];
    cf wos_w     = (cf)d_in[15];
    cf Um_w      = (cf)d_in[16];
    cf bm        = (cf)d_in[17];
    cf wm_w      = (cf)d_in[18];
    cf Uv_w      = (cf)d_in[19];
    cf bv        = (cf)d_in[20];
    cf wv_w      = (cf)d_in[21];
    cf vis_w     = (cf)d_in[22];
    cf vis_b     = (cf)d_in[23];
    cf sem_w     = (cf)d_in[24];
    cf sem_b     = (cf)d_in[25];
    cf W_ih      = (cf)d_in[26];
    cf W_hh      = (cf)d_in[27];
    cf b_ih      = (cf)d_in[28];
    cf b_hh      = (cf)d_in[29];
    cf to_word_w = (cf)d_in[30];
    cf to_word_b = (cf)d_in[31];
    cf logit_w   = (cf)d_in[32];
    cf logit_b   = (cf)d_in[33];

    // workspace layout
    char* p = (char*)d_ws;
    float* Wh = (float*)p;                     p += (size_t)B * H * 4;        // 2 MB
    __hip_bfloat16* U = (__hip_bfloat16*)p;    p += (size_t)B * NO * H * 2;   // 37.75 MB (largest U)
    __hip_bfloat16* xvis = (__hip_bfloat16*)p; p += (size_t)B * 3 * H * 2;    // 3 MB
    __hip_bfloat16* xsem = (__hip_bfloat16*)p; p += (size_t)B * 3 * S * 2;    // 1.8 MB
    __hip_bfloat16* x    = (__hip_bfloat16*)p; p += (size_t)B * (2 * H + E) * 2; // 3 MB
    float* gates = (float*)p;                  p += (size_t)B * 4 * H * 4;    // 8 MB
    __hip_bfloat16* h_ws = (__hip_bfloat16*)p; p += (size_t)B * H * 2;        // 1 MB
    __hip_bfloat16* word = (__hip_bfloat16*)p; p += (size_t)B * H * 2;        // 1 MB

    float* out_logp = (float*)d_out;
    float* out_h = out_logp + (size_t)B * V;
    float* out_c = out_h + (size_t)B * H;

    const dim3 blk(TPB);
    auto gg = [](int M, int N) { return dim3((unsigned)((N + 127) / 128), (unsigned)((M + 127) / 128)); };

    // 1. Wh = h0 @ W_w^T  (fp32 out)
    gemm_bt<float, float, float, false, false><<<gg(B, H), blk, 0, stream>>>(
        h0, H, W_w, H, Wh, H, nullptr, B, H, H);

    // 2. objects attention -> xvis[:, 1024:1536]
    gemm_bt<float, float, __hip_bfloat16, false, false><<<gg(B * NO, H), blk, 0, stream>>>(
        objects, H, Uo_w, H, U, H, nullptr, B * NO, H, H);
    attn_kernel<<<B, blk, 0, stream>>>(Wh, U, objects, bo, wo_w, xvis + 2 * H, 3 * H, NO, H);

    // 3. motion attention -> xvis[:, 512:1024]
    gemm_bt<float, float, __hip_bfloat16, false, false><<<gg(B * NA, H), blk, 0, stream>>>(
        action, H, Um_w, H, U, H, nullptr, B * NA, H, H);
    attn_kernel<<<B, blk, 0, stream>>>(Wh, U, action, bm, wm_w, xvis + H, 3 * H, NA, H);

    // 4. video attention -> xvis[:, 0:512]
    gemm_bt<float, float, __hip_bfloat16, false, false><<<gg(B * NV, H), blk, 0, stream>>>(
        video, H, Uv_w, H, U, H, nullptr, B * NV, H, H);
    attn_kernel<<<B, blk, 0, stream>>>(Wh, U, video, bv, wv_w, xvis, 3 * H, NV, H);

    // 5. semantic attention -> xsem[:, 0:300]
    gemm_bt<float, float, __hip_bfloat16, false, false><<<gg(B * NOS, H), blk, 0, stream>>>(
        obj_sem, S, Uos_w, S, U, H, nullptr, B * NOS, H, S);
    attn_kernel<<<B, blk, 0, stream>>>(Wh, U, obj_sem, bos, wos_w, xsem, 3 * S, NOS, S);

    // 6. concat copies (fp32 -> bf16)
    cvt_copy_2d<<<(B * S + TPB - 1) / TPB, blk, 0, stream>>>(act_sem, S, xsem + S, 3 * S, B, S);
    cvt_copy_2d<<<(B * S + TPB - 1) / TPB, blk, 0, stream>>>(vid_sem, S, xsem + 2 * S, 3 * S, B, S);
    cvt_copy_2d<<<(B * E + TPB - 1) / TPB, blk, 0, stream>>>(embed, E, x + 2 * H, 2 * H + E, B, E);

    // 7. visual = xvis @ vis_w^T + vis_b  -> x[:, 0:512]
    gemm_bt<__hip_bfloat16, float, __hip_bfloat16, false, true><<<gg(B, H), blk, 0, stream>>>(
        xvis, 3 * H, vis_w, 3 * H, x, 2 * H + E, vis_b, B, H, 3 * H);
    // 8. sem = xsem @ sem_w^T + sem_b    -> x[:, 512:1024]
    gemm_bt<__hip_bfloat16, float, __hip_bfloat16, false, true><<<gg(B, H), blk, 0, stream>>>(
        xsem, 3 * S, sem_w, 3 * S, x + H, 2 * H + E, sem_b, B, H, 3 * S);

    // 9. gates = x @ W_ih^T ; gates += h0 @ W_hh^T  (fp32)
    gemm_bt<__hip_bfloat16, float, float, false, false><<<gg(B, 4 * H), blk, 0, stream>>>(
        x, 2 * H + E, W_ih, 2 * H + E, gates, 4 * H, nullptr, B, 4 * H, 2 * H + E);
    gemm_bt<float, float, float, true, false><<<gg(B, 4 * H), blk, 0, stream>>>(
        h0, H, W_hh, H, gates, 4 * H, nullptr, B, 4 * H, H);

    // 10. LSTM pointwise -> out_h, out_c (fp32), h_ws (bf16)
    lstm_kernel<<<(B * H) / TPB, blk, 0, stream>>>(gates, b_ih, b_hh, c0, out_h, out_c, h_ws);

    // 11. word = h @ to_word_w^T + to_word_b (bf16)
    gemm_bt<__hip_bfloat16, float, __hip_bfloat16, false, true><<<gg(B, E), blk, 0, stream>>>(
        h_ws, H, to_word_w, H, word, E, to_word_b, B, E, H);

    // 12. logits = word @ logit_w^T + logit_b -> d_out (fp32, raw logits)
    gemm_bt<__hip_bfloat16, float, float, false, true><<<gg(B, V), blk, 0, stream>>>(
        word, E, logit_w, E, out_logp, V, logit_b, B, V, E);

    // 13. in-place row log-softmax
    logsoftmax_kernel<<<B, blk, 0, stream>>>(out_logp, V);
}